// Round 9
// baseline (421.863 us; speedup 1.0000x reference)
//
#include <hip/hip_runtime.h>

// ---------- common ----------
typedef __bf16 bfv8 __attribute__((ext_vector_type(8)));
typedef float f32x4 __attribute__((ext_vector_type(4)));

#define DMODEL 2048
#define NHEADS 16
#define HEADD 128
#define SEQ 2048
#define BATCH 2
#define MROWS (BATCH * SEQ)   // 4096

__device__ __forceinline__ unsigned short f2bf(float f) {
    unsigned int x = __float_as_uint(f);
    x += 0x7fffu + ((x >> 16) & 1u);   // round-to-nearest-even
    return (unsigned short)(x >> 16);
}
__device__ __forceinline__ float bf2f(unsigned short u) {
    return __uint_as_float((unsigned int)u << 16);
}
__device__ __forceinline__ unsigned int pk2(float a, float b) {
    return (unsigned int)f2bf(a) | ((unsigned int)f2bf(b) << 16);
}

// ---------- fused fp32 -> bf16 convert for x + 4 weights, + RoPE cos/sin table ----------
// Table blocks (bid >= 24576): 131072 (s,lane) entries as float2(cos,sin) into rtab
// (= d_out, dead until gemm_bt). Moves 16.8M epilogue sincosf -> 131K here.
__global__ __launch_bounds__(256) void cvt_all(const float* __restrict__ x,
                                               const float* __restrict__ wq,
                                               const float* __restrict__ wk,
                                               const float* __restrict__ wv,
                                               const float* __restrict__ wo,
                                               unsigned short* __restrict__ dst,
                                               float2* __restrict__ rtab) {
    int bid = blockIdx.x;
    if (bid >= 24576) {   // RoPE table: 128 blocks x 256 thr x 4 entries
        int idx0 = (bid - 24576) * 1024 + threadIdx.x * 4;
#pragma unroll
        for (int k = 0; k < 4; ++k) {
            int idx = idx0 + k;
            int s = idx >> 6, ln = idx & 63;
            float inv = powf(10000.0f, -(float)ln * (1.0f / 64.0f));
            float ang = (float)s * inv;
            float sn, c;
            sincosf(ang, &sn, &c);
            rtab[idx] = make_float2(c, sn);
        }
        return;
    }
    const float* s;
    int off;
    if (bid < 8192)       { s = x;  off = bid; }
    else if (bid < 12288) { s = wq; off = bid - 8192; }
    else if (bid < 16384) { s = wk; off = bid - 12288; }
    else if (bid < 20480) { s = wv; off = bid - 16384; }
    else                  { s = wo; off = bid - 20480; }
    int i = off * 1024 + threadIdx.x * 4;
    float4 v = *(const float4*)(s + i);
    ushort4 o;
    o.x = f2bf(v.x); o.y = f2bf(v.y); o.z = f2bf(v.z); o.w = f2bf(v.w);
    *(ushort4*)(dst + (size_t)bid * 1024 + threadIdx.x * 4) = o;
}

// ============================================================
// global_load_lds staging into XOR-swizzled unpadded LDS.
// CPRL = log2(16B-chunks per row). Stored chunk c holds global
// chunk g = c ^ (row & 7).  128B rows -> proven 0 bank conflicts.
// ============================================================
template <int CPRL, int ITERS>
__device__ __forceinline__ void stage_n(const unsigned short* __restrict__ gbase,
                                        unsigned short* lds, size_t strideShorts,
                                        int wave, int lane) {
#pragma unroll
    for (int i = 0; i < ITERS; ++i) {
        int L = wave * (64 * ITERS) + i * 64 + lane;
        int m = L >> CPRL, c = L & ((1 << CPRL) - 1);
        int g = c ^ (m & 7);
        const unsigned short* gp = gbase + (size_t)m * strideShorts + g * 8;
        __builtin_amdgcn_global_load_lds(
            (const __attribute__((address_space(1))) unsigned int*)gp,
            (__attribute__((address_space(3))) unsigned int*)(lds + (size_t)(wave * (64 * ITERS) + i * 64) * 8),
            16, 0, 0);
    }
}

#define GBK 64
#define QNT (DMODEL / 64)   // 32 K-tiles

// ============================================================
// fused QKV GEMM + RoPE + per-head LayerNorm epilogue.
// 256x256 tile / 8-wave / round-2 K-loop (best measured: 125.7 us).
// r8 fused epilogue cost +49us, dominated by 64 sincosf/thread
// (VALUBusy 21%). r9: table lookup (rtab, precomputed in cvt_all)
// replaces sincosf; everything else identical to r8.
//
// K-loop schedule per tile t (slot s=t&1), race-free, r2-proven:
//   PhA: stage hB0(t+1)->s^1; reads a03/b01; 16 MFMA (prio 1)
//   PhB: stage hB1(t+1)->s^1; reads a47/b23; 16 MFMA
//   lgkm(0); barrier   <- all waves done reading slot s
//   PhC: stage hA0(t+2)->s; 16 MFMA    PhD: stage hA1(t+2)->s; 16 MFMA
//   vmcnt(4); barrier  <- tile t+1 landed; hA(t+2) in flight
// LDS union: K-loop LA|LB = 128 KB; epilogue LC = 256x264x2 = 132 KB.
// ============================================================
__global__ __launch_bounds__(512, 2) void gemm_qkv(const unsigned short* __restrict__ A,
                                                   const unsigned short* __restrict__ Bw,
                                                   unsigned short* __restrict__ Qb,
                                                   unsigned short* __restrict__ Kb,
                                                   unsigned short* __restrict__ VT,
                                                   const float* __restrict__ qnw,
                                                   const float* __restrict__ knw,
                                                   const float2* __restrict__ rtab) {
    __shared__ __align__(16) unsigned char LDSraw[135168];
    unsigned short (*LA)[256 * 64] = (unsigned short (*)[256 * 64])(LDSraw);           // [2][16384]
    unsigned short (*LB)[256 * 64] = (unsigned short (*)[256 * 64])(LDSraw + 65536);   // [2][16384]
    unsigned short* LC = (unsigned short*)LDSraw;                                      // [256][264]
    const int K = DMODEL;
    int tid  = threadIdx.x;
    int wave = tid >> 6, lane = tid & 63;
    int wr = wave >> 2, wc = wave & 3;        // 2 x 4 wave grid
    int wm = wr * 128, wn = wc * 64;          // per-wave C = 128 x 64
    int lr = lane & 15, lg = lane >> 4, lsw = lr & 7;
    int bm = blockIdx.y * 256, bn = blockIdx.x * 256;

    const unsigned short* Ab = A  + (size_t)bm * K;
    const unsigned short* Bb = Bw + (size_t)bn * K;

    f32x4 acc[8][4];
    f32x4 z = {0.f, 0.f, 0.f, 0.f};
#pragma unroll
    for (int i = 0; i < 8; ++i)
#pragma unroll
        for (int j = 0; j < 4; ++j) acc[i][j] = z;

    // ---- prologue: A(0) both halves, B(0) both halves, A(1) both halves (12 loads/thread)
    stage_n<3, 2>(Ab,                        LA[0],            K, wave, lane);
    stage_n<3, 2>(Ab + (size_t)128 * K,      LA[0] + 128 * 64, K, wave, lane);
    stage_n<3, 2>(Bb,                        LB[0],            K, wave, lane);
    stage_n<3, 2>(Bb + (size_t)128 * K,      LB[0] + 128 * 64, K, wave, lane);
    stage_n<3, 2>(Ab + 64,                   LA[1],            K, wave, lane);
    stage_n<3, 2>(Ab + (size_t)128 * K + 64, LA[1] + 128 * 64, K, wave, lane);
    asm volatile("s_waitcnt vmcnt(4)" ::: "memory");   // tile 0 landed; hA(1) in flight
    __builtin_amdgcn_s_barrier();
    __builtin_amdgcn_sched_barrier(0);

#pragma unroll 2
    for (int t = 0; t < QNT; ++t) {
        const unsigned short* As = LA[t & 1];
        const unsigned short* Bs = LB[t & 1];
        unsigned short* AsN = LA[t & 1];           // A(t+2) -> same slot
        unsigned short* BsN = LB[(t & 1) ^ 1];     // B(t+1) -> other slot
        int tA = t + 2; if (tA >= QNT) tA = t;     // tail dummies keep vmcnt uniform
        int tB = t + 1; if (tB >= QNT) tB = t - 1; // (same parity -> same slot, no reader)

        bfv8 a03[4][2], a47[4][2], b01[2][2], b23[2][2];

        // ---- phase A: stage hB0(t+1); read a[0..3], b[0..1]; MFMA (i0-3 x j0-1)
        stage_n<3, 2>(Bb + (size_t)tB * 64, BsN, K, wave, lane);
#pragma unroll
        for (int i = 0; i < 4; ++i)
#pragma unroll
            for (int ks = 0; ks < 2; ++ks)
                a03[i][ks] = *(const bfv8*)&As[(wm + i * 16 + lr) * 64 + ((ks * 4 + lg) ^ lsw) * 8];
#pragma unroll
        for (int j = 0; j < 2; ++j)
#pragma unroll
            for (int ks = 0; ks < 2; ++ks)
                b01[j][ks] = *(const bfv8*)&Bs[(wn + j * 16 + lr) * 64 + ((ks * 4 + lg) ^ lsw) * 8];
        __builtin_amdgcn_sched_barrier(0);
        __builtin_amdgcn_s_setprio(1);
#pragma unroll
        for (int i = 0; i < 4; ++i)
#pragma unroll
            for (int j = 0; j < 2; ++j)
#pragma unroll
                for (int ks = 0; ks < 2; ++ks)
                    acc[i][j] = __builtin_amdgcn_mfma_f32_16x16x32_bf16(a03[i][ks], b01[j][ks], acc[i][j], 0, 0, 0);
        __builtin_amdgcn_s_setprio(0);
        __builtin_amdgcn_sched_barrier(0);

        // ---- phase B: stage hB1(t+1); read a[4..7], b[2..3]; MFMA (i0-3 x j2-3)
        stage_n<3, 2>(Bb + (size_t)128 * K + tB * 64, BsN + 128 * 64, K, wave, lane);
#pragma unroll
        for (int i = 0; i < 4; ++i)
#pragma unroll
            for (int ks = 0; ks < 2; ++ks)
                a47[i][ks] = *(const bfv8*)&As[(wm + 64 + i * 16 + lr) * 64 + ((ks * 4 + lg) ^ lsw) * 8];
#pragma unroll
        for (int j = 0; j < 2; ++j)
#pragma unroll
            for (int ks = 0; ks < 2; ++ks)
                b23[j][ks] = *(const bfv8*)&Bs[(wn + 32 + j * 16 + lr) * 64 + ((ks * 4 + lg) ^ lsw) * 8];
        __builtin_amdgcn_sched_barrier(0);
        __builtin_amdgcn_s_setprio(1);
#pragma unroll
        for (int i = 0; i < 4; ++i)
#pragma unroll
            for (int j = 0; j < 2; ++j)
#pragma unroll
                for (int ks = 0; ks < 2; ++ks)
                    acc[i][2 + j] = __builtin_amdgcn_mfma_f32_16x16x32_bf16(a03[i][ks], b23[j][ks], acc[i][2 + j], 0, 0, 0);
        __builtin_amdgcn_s_setprio(0);
        __builtin_amdgcn_sched_barrier(0);

        asm volatile("s_waitcnt lgkmcnt(0)" ::: "memory");  // my reads of slot s drained
        __builtin_amdgcn_s_barrier();                        // ... all waves' reads drained
        __builtin_amdgcn_sched_barrier(0);

        // ---- phase C: stage hA0(t+2) into freed slot; MFMA (i4-7 x j0-1)
        stage_n<3, 2>(Ab + (size_t)tA * 64, AsN, K, wave, lane);
        __builtin_amdgcn_sched_barrier(0);
        __builtin_amdgcn_s_setprio(1);
#pragma unroll
        for (int i = 0; i < 4; ++i)
#pragma unroll
            for (int j = 0; j < 2; ++j)
#pragma unroll
                for (int ks = 0; ks < 2; ++ks)
                    acc[4 + i][j] = __builtin_amdgcn_mfma_f32_16x16x32_bf16(a47[i][ks], b01[j][ks], acc[4 + i][j], 0, 0, 0);
        __builtin_amdgcn_s_setprio(0);
        __builtin_amdgcn_sched_barrier(0);

        // ---- phase D: stage hA1(t+2); MFMA (i4-7 x j2-3)
        stage_n<3, 2>(Ab + (size_t)128 * K + tA * 64, AsN + 128 * 64, K, wave, lane);
        __builtin_amdgcn_sched_barrier(0);
        __builtin_amdgcn_s_setprio(1);
#pragma unroll
        for (int i = 0; i < 4; ++i)
#pragma unroll
            for (int j = 0; j < 2; ++j)
#pragma unroll
                for (int ks = 0; ks < 2; ++ks)
                    acc[4 + i][2 + j] = __builtin_amdgcn_mfma_f32_16x16x32_bf16(a47[i][ks], b23[j][ks], acc[4 + i][2 + j], 0, 0, 0);
        __builtin_amdgcn_s_setprio(0);
        __builtin_amdgcn_sched_barrier(0);

        asm volatile("s_waitcnt vmcnt(4)" ::: "memory");   // tile t+1 landed; hA(t+2) in flight
        __builtin_amdgcn_s_barrier();
        __builtin_amdgcn_sched_barrier(0);
    }
    asm volatile("s_waitcnt vmcnt(0)" ::: "memory");  // drain tail dummies before LDS reuse

    // ---- epilogue
    int region = bn >> 11;          // block-uniform: 0=Q 1=K 2=V (2048 % 256 == 0)
    int nloc   = bn & 2047;
    if (region < 2) {
        // stage fragments to padded LDS for cross-wave RoPE+LayerNorm
        __syncthreads();   // all waves past K-loop before LC overwrites LA/LB
#pragma unroll
        for (int i = 0; i < 8; ++i)
#pragma unroll
            for (int j = 0; j < 4; ++j)
#pragma unroll
                for (int r = 0; r < 4; ++r)
                    LC[(wm + lg * 4 + i * 16 + r) * 264 + wn + j * 16 + lr] = f2bf(acc[i][j][r]);
        __syncthreads();
        unsigned short* C = region ? Kb : Qb;
        const float* w = region ? knw : qnw;
        float scale = region ? 1.0f : 0.08838834764831845f;   // fold 1/sqrt(128) into Q
        float2 wv = *(const float2*)(w + lane * 2);
        int h0 = nloc >> 7;   // first of the 2 heads this block owns
#pragma unroll 1
        for (int it = 0; it < 64; ++it) {
            int p  = wave * 64 + it;          // 512 (row, head) pairs / 8 waves
            int rl = p >> 1, hl = p & 1;
            ushort2 xv = *(const ushort2*)&LC[rl * 264 + hl * 128 + lane * 2];
            float x0 = bf2f(xv.x), x1 = bf2f(xv.y);
            int grow = bm + rl;
            int s = grow & (SEQ - 1);
            float2 cs = rtab[(size_t)s * 64 + lane];   // (cos, sin) - coalesced, L2-hot
            float y0 = x0 * cs.x - x1 * cs.y;
            float y1 = x0 * cs.y + x1 * cs.x;
            float sum = y0 + y1;
            float sq  = y0 * y0 + y1 * y1;
#pragma unroll
            for (int o = 32; o >= 1; o >>= 1) {
                sum += __shfl_xor(sum, o);
                sq  += __shfl_xor(sq, o);
            }
            float mu  = sum * (1.0f / 128.0f);
            float var = sq * (1.0f / 128.0f) - mu * mu;
            float rs  = rsqrtf(var + 1e-5f) * scale;
            ushort2 ov;
            ov.x = f2bf((y0 - mu) * rs * wv.x);
            ov.y = f2bf((y1 - mu) * rs * wv.y);
            *(ushort2*)&C[(size_t)grow * DMODEL + (h0 + hl) * HEADD + lane * 2] = ov;
        }
    } else {
        int orow0 = bm + wm + lg * 4;
#pragma unroll
        for (int i = 0; i < 8; ++i) {
            int row = orow0 + i * 16;
            int bb = row >> 11, ss = row & (SEQ - 1);
#pragma unroll
            for (int j = 0; j < 4; ++j) {
                int col = nloc + wn + j * 16 + lr;
                int hh = col >> 7, dd = col & (HEADD - 1);
                ushort4 o4;
                o4.x = f2bf(acc[i][j][0]);
                o4.y = f2bf(acc[i][j][1]);
                o4.z = f2bf(acc[i][j][2]);
                o4.w = f2bf(acc[i][j][3]);
                *(ushort4*)(VT + ((size_t)((bb * NHEADS + hh) * HEADD + dd)) * SEQ + ss) = o4;
            }
        }
    }
}

// ---------- plain GEMM (fp32 out): C[M][N] = A[M][K] * Bw[N][K]^T ----------
__global__ __launch_bounds__(256) void gemm_bt(const unsigned short* __restrict__ A,
                                               const unsigned short* __restrict__ Bw,
                                               float* __restrict__ C,
                                               int M, int N, int K) {
    __shared__ __align__(16) unsigned short As[128 * 64];
    __shared__ __align__(16) unsigned short Bs[128 * 64];
    int tid  = threadIdx.x;
    int bm   = blockIdx.y * 128, bn = blockIdx.x * 128;
    int wave = tid >> 6, lane = tid & 63;
    int wm   = (wave >> 1) * 64, wn = (wave & 1) * 64;
    int lr   = lane & 15, lg = lane >> 4;

    f32x4 acc[4][4];
    f32x4 z = {0.f, 0.f, 0.f, 0.f};
#pragma unroll
    for (int i = 0; i < 4; ++i)
#pragma unroll
        for (int j = 0; j < 4; ++j) acc[i][j] = z;

    const unsigned short* Ab = A  + (size_t)bm * K;
    const unsigned short* Bb = Bw + (size_t)bn * K;

    for (int k0 = 0; k0 < K; k0 += GBK) {
        __syncthreads();
        stage_n<3, 4>(Ab + k0, As, K, wave, lane);
        stage_n<3, 4>(Bb + k0, Bs, K, wave, lane);
        __syncthreads();
#pragma unroll
        for (int kk = 0; kk < GBK; kk += 32) {
            int ck = (kk >> 3) + lg;
            bfv8 af[4], bf[4];
#pragma unroll
            for (int i = 0; i < 4; ++i)
                af[i] = *(const bfv8*)&As[(wm + i * 16 + lr) * 64 + (ck ^ (lr & 7)) * 8];
#pragma unroll
            for (int j = 0; j < 4; ++j)
                bf[j] = *(const bfv8*)&Bs[(wn + j * 16 + lr) * 64 + (ck ^ (lr & 7)) * 8];
#pragma unroll
            for (int i = 0; i < 4; ++i)
#pragma unroll
                for (int j = 0; j < 4; ++j)
                    acc[i][j] = __builtin_amdgcn_mfma_f32_16x16x32_bf16(af[i], bf[j], acc[i][j], 0, 0, 0);
        }
    }
    int orow0 = bm + wm + lg * 4;
    int ocol0 = bn + wn + lr;
#pragma unroll
    for (int i = 0; i < 4; ++i)
#pragma unroll
        for (int j = 0; j < 4; ++j)
#pragma unroll
            for (int r = 0; r < 4; ++r)
                C[(size_t)(orow0 + i * 16 + r) * N + ocol0 + j * 16] = acc[i][j][r];
}

// ---------- bf16 MFMA flash attention (sliding window), S^T compute ----------
#define AQT 64
#define AKT 64

__global__ __launch_bounds__(256) void attn_mfma(const unsigned short* __restrict__ qb,
                                                 const unsigned short* __restrict__ kb,
                                                 const unsigned short* __restrict__ vt,
                                                 unsigned short* __restrict__ ob,
                                                 const int* __restrict__ wptr) {
    __shared__ __align__(16) unsigned short Ks[64 * 128];    // K tile, swizzled, 16 KB
    __shared__ __align__(16) unsigned short Vs[128 * 64];    // V^T tile, swizzled, 16 KB
    __shared__ __align__(16) unsigned short Ps[4 * 16 * 64]; // per-wave P, swizzled, 8 KB
    int tid  = threadIdx.x;
    int wq   = tid >> 6, lane = tid & 63;
    int lm   = lane & 15, lg = lane >> 4;
    int lm7  = lm & 7;
    // XCD-grouped, heavy-first scheduling
    int gid  = blockIdx.x;
    int xcd  = gid & 7, slot = gid >> 3;
    int bh   = xcd * 4 + (slot >> 5);
    int b    = bh >> 4, h = bh & 15;
    int q0   = (31 - (slot & 31)) * AQT;
    int W    = *wptr;
    unsigned short* PsW = &Ps[wq * 1024];

    // Q B-fragments (16 queries/wave); 1/sqrt(d) pre-folded into Q
    bfv8 qa[4];
    {
        const unsigned short* qp = qb + (size_t)(b * SEQ + q0 + wq * 16 + lm) * DMODEL + h * HEADD + lg * 8;
#pragma unroll
        for (int kk = 0; kk < 4; ++kk) qa[kk] = *(const bfv8*)(qp + kk * 32);
    }

    f32x4 o[8];
    f32x4 z = {0.f, 0.f, 0.f, 0.f};
#pragma unroll
    for (int n = 0; n < 8; ++n) o[n] = z;
    float mrow = -1e30f, lrow = 0.f;   // per-lane state for query lm (replicated over lg)

    const unsigned short* kbase = kb + (size_t)(b * SEQ) * DMODEL + h * HEADD;
    const unsigned short* vbase = vt + (size_t)((b * NHEADS + h) * HEADD) * SEQ;

    int kt_lo = max(0, q0 - W) & ~(AKT - 1);
    int qi = q0 + wq * 16 + lm;

    for (int kt = kt_lo; kt < q0 + AQT; kt += AKT) {
        __syncthreads();
        stage_n<4, 4>(kbase + (size_t)kt * DMODEL, Ks, DMODEL, wq, lane);  // 64 x 128
        stage_n<3, 4>(vbase + kt, Vs, SEQ, wq, lane);                      // 128 x 64
        __syncthreads();

        // S^T = K Q^T : D[m=key][n=query], 64x16 per wave
        f32x4 s[4];
#pragma unroll
        for (int j = 0; j < 4; ++j) s[j] = z;
#pragma unroll
        for (int kk = 0; kk < 4; ++kk) {
#pragma unroll
            for (int j = 0; j < 4; ++j) {
                int ck = (kk * 4 + lg) ^ lm7;
                bfv8 af = *(const bfv8*)&Ks[(j * 16 + lm) * 128 + ck * 8];
                s[j] = __builtin_amdgcn_mfma_f32_16x16x32_bf16(af, qa[kk], s[j], 0, 0, 0);
            }
        }
        // mask only edge tiles (wave-uniform branch)
        if ((kt + 63 >= q0) || (kt < q0 + 63 - W)) {
#pragma unroll
            for (int j = 0; j < 4; ++j) {
                int kj0 = kt + j * 16 + lg * 4;
#pragma unroll
                for (int r = 0; r < 4; ++r) {
                    bool ok = (kj0 + r <= qi) && (kj0 + r >= qi - W);
                    s[j][r] = ok ? s[j][r] : -1e30f;
                }
            }
        }
        // online softmax: one query per lane, reduce across lg (masks 16, 32)
        float mx = -1e30f;
#pragma unroll
        for (int j = 0; j < 4; ++j)
#pragma unroll
            for (int r = 0; r < 4; ++r) mx = fmaxf(mx, s[j][r]);
        mx = fmaxf(mx, __shfl_xor(mx, 16));
        mx = fmaxf(mx, __shfl_xor(mx, 32));
        float mnew  = fmaxf(mrow, mx);
        float alpha = __expf(mrow - mnew);
        mrow = mnew;
        float ls = 0.f;
#pragma unroll
        for (int j = 0; j < 4; ++j) {
            float p0 = __expf(s[j][0] - mnew);
            float p1 = __expf(s[j][1] - mnew);
            float p2 = __expf(s[j][2] - mnew);
            float p3 = __expf(s[j][3] - mnew);
            ls += (p0 + p1) + (p2 + p3);
            // P^T C-layout rows = 4 consecutive keys -> one packed b64 store
            int c0 = (j * 2 + (lg >> 1)) ^ lm7;
            uint2 wv;
            wv.x = pk2(p0, p1);
            wv.y = pk2(p2, p3);
            *(uint2*)&PsW[lm * 64 + c0 * 8 + (lg & 1) * 4] = wv;
        }
        ls += __shfl_xor(ls, 16);
        ls += __shfl_xor(ls, 32);
        lrow = lrow * alpha + ls;
        // broadcast alpha from softmax layout (query=lm) to O layout (query=lg*4+r)
        float al[4];
#pragma unroll
        for (int r = 0; r < 4; ++r) al[r] = __shfl(alpha, lg * 4 + r);
#pragma unroll
        for (int n = 0; n < 8; ++n)
#pragma unroll
            for (int r = 0; r < 4; ++r) o[n][r] *= al[r];
        // O += P V : A = P (wave-private LDS, same-wave ordering), B = V^T
#pragma unroll
        for (int k2 = 0; k2 < 2; ++k2) {
            int cc = (k2 * 4 + lg) ^ lm7;
            bfv8 pa = *(const bfv8*)&PsW[lm * 64 + cc * 8];
#pragma unroll
            for (int n = 0; n < 8; ++n) {
                bfv8 vf = *(const bfv8*)&Vs[(n * 16 + lm) * 64 + cc * 8];
                o[n] = __builtin_amdgcn_mfma_f32_16x16x32_bf16(pa, vf, o[n], 0, 0, 0);
            }
        }
    }
    // epilogue
    float linv[4];
#pragma unroll
    for (int r = 0; r < 4; ++r) linv[r] = 1.0f / __shfl(lrow, lg * 4 + r);
    int qrow = q0 + wq * 16 + lg * 4;
    unsigned short* op = ob + (size_t)(b * SEQ + qrow) * DMODEL + h * HEADD + lm;
#pragma unroll
    for (int n = 0; n < 8; ++n)
#pragma unroll
        for (int r = 0; r < 4; ++r)
            op[(size_t)r * DMODEL + n * 16] = f2bf(o[n][r] * linv[r]);
}

// ---------- launch ----------
extern "C" void kernel_launch(void* const* d_in, const int* in_sizes, int n_in,
                              void* d_out, int out_size, void* d_ws, size_t ws_size,
                              hipStream_t stream) {
    const float* x   = (const float*)d_in[0];
    const float* wq  = (const float*)d_in[1];
    const float* wk  = (const float*)d_in[2];
    const float* wv  = (const float*)d_in[3];
    const float* wo  = (const float*)d_in[4];
    const float* qnw = (const float*)d_in[5];
    const float* knw = (const float*)d_in[6];
    const int*   wsz = (const int*)d_in[7];
    float* out = (float*)d_out;

    // workspace layout (~101 MB); cvt_all dst = [xb | w1 | w2 | w3 | w4] contiguous
    char* ws = (char*)d_ws;
    unsigned short* xb  = (unsigned short*)(ws);                 // 16.78 MB (x bf16; reused for attn out)
    unsigned short* w1  = (unsigned short*)(ws + 16777216);      // wq \  contiguous ->
    unsigned short* w4  = (unsigned short*)(ws + 41943040);      // wo
    unsigned short* qbf = (unsigned short*)(ws + 50331648);      // 16.78 MB bf16 Q
    unsigned short* kbf = (unsigned short*)(ws + 67108864);      // 16.78 MB bf16 K
    unsigned short* vtb = (unsigned short*)(ws + 83886080);      // 16.78 MB bf16 V^T
    float2* rtab = (float2*)d_out;   // RoPE table (1 MB) in d_out - dead until gemm_bt writes it

    cvt_all<<<24704, 256, 0, stream>>>(x, wq, wk, wv, wo, xb, rtab);

    gemm_qkv<<<dim3(3 * DMODEL / 256, MROWS / 256), 512, 0, stream>>>(xb, w1, qbf, kbf, vtb, qnw, knw,
                                                                      (const float2*)rtab);

    attn_mfma<<<(SEQ / AQT) * NHEADS * BATCH, 256, 0, stream>>>(qbf, kbf, vtb, xb, wsz);

    gemm_bt<<<dim3(DMODEL / 128, MROWS / 128), 256, 0, stream>>>(xb, w4, out, MROWS, DMODEL, DMODEL);
}

// Round 10
// 396.840 us; speedup vs baseline: 1.0631x; 1.0631x over previous
//
#include <hip/hip_runtime.h>

// ---------- common ----------
typedef __bf16 bfv8 __attribute__((ext_vector_type(8)));
typedef float f32x4 __attribute__((ext_vector_type(4)));

#define DMODEL 2048
#define NHEADS 16
#define HEADD 128
#define SEQ 2048
#define BATCH 2
#define MROWS (BATCH * SEQ)   // 4096

__device__ __forceinline__ unsigned short f2bf(float f) {
    unsigned int x = __float_as_uint(f);
    x += 0x7fffu + ((x >> 16) & 1u);   // round-to-nearest-even
    return (unsigned short)(x >> 16);
}
__device__ __forceinline__ float bf2f(unsigned short u) {
    return __uint_as_float((unsigned int)u << 16);
}
__device__ __forceinline__ unsigned int pk2(float a, float b) {
    return (unsigned int)f2bf(a) | ((unsigned int)f2bf(b) << 16);
}

// ---------- fused fp32 -> bf16 convert for x + 4 weights, + RoPE cos/sin table ----------
// Table blocks (bid >= 24576): 131072 (s,lane) entries as float2(cos,sin) into rtab
// (= d_out, dead until gemm_bt).
__global__ __launch_bounds__(256) void cvt_all(const float* __restrict__ x,
                                               const float* __restrict__ wq,
                                               const float* __restrict__ wk,
                                               const float* __restrict__ wv,
                                               const float* __restrict__ wo,
                                               unsigned short* __restrict__ dst,
                                               float2* __restrict__ rtab) {
    int bid = blockIdx.x;
    if (bid >= 24576) {   // RoPE table: 128 blocks x 256 thr x 4 entries
        int idx0 = (bid - 24576) * 1024 + threadIdx.x * 4;
#pragma unroll
        for (int k = 0; k < 4; ++k) {
            int idx = idx0 + k;
            int s = idx >> 6, ln = idx & 63;
            float inv = powf(10000.0f, -(float)ln * (1.0f / 64.0f));
            float ang = (float)s * inv;
            float sn, c;
            sincosf(ang, &sn, &c);
            rtab[idx] = make_float2(c, sn);
        }
        return;
    }
    const float* s;
    int off;
    if (bid < 8192)       { s = x;  off = bid; }
    else if (bid < 12288) { s = wq; off = bid - 8192; }
    else if (bid < 16384) { s = wk; off = bid - 12288; }
    else if (bid < 20480) { s = wv; off = bid - 16384; }
    else                  { s = wo; off = bid - 20480; }
    int i = off * 1024 + threadIdx.x * 4;
    float4 v = *(const float4*)(s + i);
    ushort4 o;
    o.x = f2bf(v.x); o.y = f2bf(v.y); o.z = f2bf(v.z); o.w = f2bf(v.w);
    *(ushort4*)(dst + (size_t)bid * 1024 + threadIdx.x * 4) = o;
}

// ============================================================
// global_load_lds staging into XOR-swizzled unpadded LDS.
// CPRL = log2(16B-chunks per row). Stored chunk c holds global
// chunk g = c ^ (row & 7).  128B rows -> proven 0 bank conflicts.
// ============================================================
template <int CPRL, int ITERS>
__device__ __forceinline__ void stage_n(const unsigned short* __restrict__ gbase,
                                        unsigned short* lds, size_t strideShorts,
                                        int wave, int lane) {
#pragma unroll
    for (int i = 0; i < ITERS; ++i) {
        int L = wave * (64 * ITERS) + i * 64 + lane;
        int m = L >> CPRL, c = L & ((1 << CPRL) - 1);
        int g = c ^ (m & 7);
        const unsigned short* gp = gbase + (size_t)m * strideShorts + g * 8;
        __builtin_amdgcn_global_load_lds(
            (const __attribute__((address_space(1))) unsigned int*)gp,
            (__attribute__((address_space(3))) unsigned int*)(lds + (size_t)(wave * (64 * ITERS) + i * 64) * 8),
            16, 0, 0);
    }
}

#define GBK 64
#define QNT (DMODEL / 64)   // 32 K-tiles

// ============================================================
// fused QKV GEMM + RoPE + per-head LayerNorm epilogue.
// 256x256 tile / 8-wave / round-2 K-loop (best measured: 125.7 us).
// r8 epilogue cost +49us. r9 (rtab) showed the cost is NOT sincosf
// VALU but per-wave serial chain latency: 64 iters x ~550cyc chain
// (ds_read -> rtab load -> 6-level shfl x2 -> store) with unroll 1 =
// ~15us/wave wall, unhidden by TLP. r10: 4-wide ILP batching - load
// phase issues 4 independent ds_read+rtab, then 4 independent
// reduce chains interleave in the scheduler. Same math, same order,
// bitwise-identical output.
//
// K-loop schedule per tile t (slot s=t&1), race-free, r2-proven:
//   PhA: stage hB0(t+1)->s^1; reads a03/b01; 16 MFMA (prio 1)
//   PhB: stage hB1(t+1)->s^1; reads a47/b23; 16 MFMA
//   lgkm(0); barrier   <- all waves done reading slot s
//   PhC: stage hA0(t+2)->s; 16 MFMA    PhD: stage hA1(t+2)->s; 16 MFMA
//   vmcnt(4); barrier  <- tile t+1 landed; hA(t+2) in flight
// LDS union: K-loop LA|LB = 128 KB; epilogue LC = 256x264x2 = 132 KB.
// ============================================================
__global__ __launch_bounds__(512, 2) void gemm_qkv(const unsigned short* __restrict__ A,
                                                   const unsigned short* __restrict__ Bw,
                                                   unsigned short* __restrict__ Qb,
                                                   unsigned short* __restrict__ Kb,
                                                   unsigned short* __restrict__ VT,
                                                   const float* __restrict__ qnw,
                                                   const float* __restrict__ knw,
                                                   const float2* __restrict__ rtab) {
    __shared__ __align__(16) unsigned char LDSraw[135168];
    unsigned short (*LA)[256 * 64] = (unsigned short (*)[256 * 64])(LDSraw);           // [2][16384]
    unsigned short (*LB)[256 * 64] = (unsigned short (*)[256 * 64])(LDSraw + 65536);   // [2][16384]
    unsigned short* LC = (unsigned short*)LDSraw;                                      // [256][264]
    const int K = DMODEL;
    int tid  = threadIdx.x;
    int wave = tid >> 6, lane = tid & 63;
    int wr = wave >> 2, wc = wave & 3;        // 2 x 4 wave grid
    int wm = wr * 128, wn = wc * 64;          // per-wave C = 128 x 64
    int lr = lane & 15, lg = lane >> 4, lsw = lr & 7;
    int bm = blockIdx.y * 256, bn = blockIdx.x * 256;

    const unsigned short* Ab = A  + (size_t)bm * K;
    const unsigned short* Bb = Bw + (size_t)bn * K;

    f32x4 acc[8][4];
    f32x4 z = {0.f, 0.f, 0.f, 0.f};
#pragma unroll
    for (int i = 0; i < 8; ++i)
#pragma unroll
        for (int j = 0; j < 4; ++j) acc[i][j] = z;

    // ---- prologue: A(0) both halves, B(0) both halves, A(1) both halves (12 loads/thread)
    stage_n<3, 2>(Ab,                        LA[0],            K, wave, lane);
    stage_n<3, 2>(Ab + (size_t)128 * K,      LA[0] + 128 * 64, K, wave, lane);
    stage_n<3, 2>(Bb,                        LB[0],            K, wave, lane);
    stage_n<3, 2>(Bb + (size_t)128 * K,      LB[0] + 128 * 64, K, wave, lane);
    stage_n<3, 2>(Ab + 64,                   LA[1],            K, wave, lane);
    stage_n<3, 2>(Ab + (size_t)128 * K + 64, LA[1] + 128 * 64, K, wave, lane);
    asm volatile("s_waitcnt vmcnt(4)" ::: "memory");   // tile 0 landed; hA(1) in flight
    __builtin_amdgcn_s_barrier();
    __builtin_amdgcn_sched_barrier(0);

#pragma unroll 2
    for (int t = 0; t < QNT; ++t) {
        const unsigned short* As = LA[t & 1];
        const unsigned short* Bs = LB[t & 1];
        unsigned short* AsN = LA[t & 1];           // A(t+2) -> same slot
        unsigned short* BsN = LB[(t & 1) ^ 1];     // B(t+1) -> other slot
        int tA = t + 2; if (tA >= QNT) tA = t;     // tail dummies keep vmcnt uniform
        int tB = t + 1; if (tB >= QNT) tB = t - 1; // (same parity -> same slot, no reader)

        bfv8 a03[4][2], a47[4][2], b01[2][2], b23[2][2];

        // ---- phase A: stage hB0(t+1); read a[0..3], b[0..1]; MFMA (i0-3 x j0-1)
        stage_n<3, 2>(Bb + (size_t)tB * 64, BsN, K, wave, lane);
#pragma unroll
        for (int i = 0; i < 4; ++i)
#pragma unroll
            for (int ks = 0; ks < 2; ++ks)
                a03[i][ks] = *(const bfv8*)&As[(wm + i * 16 + lr) * 64 + ((ks * 4 + lg) ^ lsw) * 8];
#pragma unroll
        for (int j = 0; j < 2; ++j)
#pragma unroll
            for (int ks = 0; ks < 2; ++ks)
                b01[j][ks] = *(const bfv8*)&Bs[(wn + j * 16 + lr) * 64 + ((ks * 4 + lg) ^ lsw) * 8];
        __builtin_amdgcn_sched_barrier(0);
        __builtin_amdgcn_s_setprio(1);
#pragma unroll
        for (int i = 0; i < 4; ++i)
#pragma unroll
            for (int j = 0; j < 2; ++j)
#pragma unroll
                for (int ks = 0; ks < 2; ++ks)
                    acc[i][j] = __builtin_amdgcn_mfma_f32_16x16x32_bf16(a03[i][ks], b01[j][ks], acc[i][j], 0, 0, 0);
        __builtin_amdgcn_s_setprio(0);
        __builtin_amdgcn_sched_barrier(0);

        // ---- phase B: stage hB1(t+1); read a[4..7], b[2..3]; MFMA (i0-3 x j2-3)
        stage_n<3, 2>(Bb + (size_t)128 * K + tB * 64, BsN + 128 * 64, K, wave, lane);
#pragma unroll
        for (int i = 0; i < 4; ++i)
#pragma unroll
            for (int ks = 0; ks < 2; ++ks)
                a47[i][ks] = *(const bfv8*)&As[(wm + 64 + i * 16 + lr) * 64 + ((ks * 4 + lg) ^ lsw) * 8];
#pragma unroll
        for (int j = 0; j < 2; ++j)
#pragma unroll
            for (int ks = 0; ks < 2; ++ks)
                b23[j][ks] = *(const bfv8*)&Bs[(wn + 32 + j * 16 + lr) * 64 + ((ks * 4 + lg) ^ lsw) * 8];
        __builtin_amdgcn_sched_barrier(0);
        __builtin_amdgcn_s_setprio(1);
#pragma unroll
        for (int i = 0; i < 4; ++i)
#pragma unroll
            for (int j = 0; j < 2; ++j)
#pragma unroll
                for (int ks = 0; ks < 2; ++ks)
                    acc[i][2 + j] = __builtin_amdgcn_mfma_f32_16x16x32_bf16(a03[i][ks], b23[j][ks], acc[i][2 + j], 0, 0, 0);
        __builtin_amdgcn_s_setprio(0);
        __builtin_amdgcn_sched_barrier(0);

        asm volatile("s_waitcnt lgkmcnt(0)" ::: "memory");  // my reads of slot s drained
        __builtin_amdgcn_s_barrier();                        // ... all waves' reads drained
        __builtin_amdgcn_sched_barrier(0);

        // ---- phase C: stage hA0(t+2) into freed slot; MFMA (i4-7 x j0-1)
        stage_n<3, 2>(Ab + (size_t)tA * 64, AsN, K, wave, lane);
        __builtin_amdgcn_sched_barrier(0);
        __builtin_amdgcn_s_setprio(1);
#pragma unroll
        for (int i = 0; i < 4; ++i)
#pragma unroll
            for (int j = 0; j < 2; ++j)
#pragma unroll
                for (int ks = 0; ks < 2; ++ks)
                    acc[4 + i][j] = __builtin_amdgcn_mfma_f32_16x16x32_bf16(a47[i][ks], b01[j][ks], acc[4 + i][j], 0, 0, 0);
        __builtin_amdgcn_s_setprio(0);
        __builtin_amdgcn_sched_barrier(0);

        // ---- phase D: stage hA1(t+2); MFMA (i4-7 x j2-3)
        stage_n<3, 2>(Ab + (size_t)128 * K + tA * 64, AsN + 128 * 64, K, wave, lane);
        __builtin_amdgcn_sched_barrier(0);
        __builtin_amdgcn_s_setprio(1);
#pragma unroll
        for (int i = 0; i < 4; ++i)
#pragma unroll
            for (int j = 0; j < 2; ++j)
#pragma unroll
                for (int ks = 0; ks < 2; ++ks)
                    acc[4 + i][2 + j] = __builtin_amdgcn_mfma_f32_16x16x32_bf16(a47[i][ks], b23[j][ks], acc[4 + i][2 + j], 0, 0, 0);
        __builtin_amdgcn_s_setprio(0);
        __builtin_amdgcn_sched_barrier(0);

        asm volatile("s_waitcnt vmcnt(4)" ::: "memory");   // tile t+1 landed; hA(t+2) in flight
        __builtin_amdgcn_s_barrier();
        __builtin_amdgcn_sched_barrier(0);
    }
    asm volatile("s_waitcnt vmcnt(0)" ::: "memory");  // drain tail dummies before LDS reuse

    // ---- epilogue
    int region = bn >> 11;          // block-uniform: 0=Q 1=K 2=V (2048 % 256 == 0)
    int nloc   = bn & 2047;
    if (region < 2) {
        // stage fragments to padded LDS for cross-wave RoPE+LayerNorm
        __syncthreads();   // all waves past K-loop before LC overwrites LA/LB
#pragma unroll
        for (int i = 0; i < 8; ++i)
#pragma unroll
            for (int j = 0; j < 4; ++j)
#pragma unroll
                for (int r = 0; r < 4; ++r)
                    LC[(wm + lg * 4 + i * 16 + r) * 264 + wn + j * 16 + lr] = f2bf(acc[i][j][r]);
        __syncthreads();
        unsigned short* C = region ? Kb : Qb;
        const float* w = region ? knw : qnw;
        float scale = region ? 1.0f : 0.08838834764831845f;   // fold 1/sqrt(128) into Q
        float2 wv = *(const float2*)(w + lane * 2);
        int h0 = nloc >> 7;   // first of the 2 heads this block owns
        // 4-wide ILP batches: load phase (4 ds_read + 4 rtab, independent),
        // then 4 independent RoPE+reduce chains -> scheduler interleaves.
#pragma unroll 1
        for (int it4 = 0; it4 < 16; ++it4) {
            ushort2 xv0, xv1, xv2, xv3;
            float2 cs0, cs1, cs2, cs3;
            int p0 = wave * 64 + it4 * 4;
            int rl0 = (p0 + 0) >> 1, rl1 = (p0 + 1) >> 1, rl2 = (p0 + 2) >> 1, rl3 = (p0 + 3) >> 1;
            int hl0 = (p0 + 0) & 1,  hl1 = (p0 + 1) & 1,  hl2 = (p0 + 2) & 1,  hl3 = (p0 + 3) & 1;
            xv0 = *(const ushort2*)&LC[rl0 * 264 + hl0 * 128 + lane * 2];
            xv1 = *(const ushort2*)&LC[rl1 * 264 + hl1 * 128 + lane * 2];
            xv2 = *(const ushort2*)&LC[rl2 * 264 + hl2 * 128 + lane * 2];
            xv3 = *(const ushort2*)&LC[rl3 * 264 + hl3 * 128 + lane * 2];
            cs0 = rtab[(size_t)((bm + rl0) & (SEQ - 1)) * 64 + lane];
            cs1 = rtab[(size_t)((bm + rl1) & (SEQ - 1)) * 64 + lane];
            cs2 = rtab[(size_t)((bm + rl2) & (SEQ - 1)) * 64 + lane];
            cs3 = rtab[(size_t)((bm + rl3) & (SEQ - 1)) * 64 + lane];
#define RLN_BODY(XV, CS, RL, HL)                                               \
            {                                                                  \
                float x0 = bf2f((XV).x), x1 = bf2f((XV).y);                    \
                float y0 = x0 * (CS).x - x1 * (CS).y;                          \
                float y1 = x0 * (CS).y + x1 * (CS).x;                          \
                float sum = y0 + y1;                                           \
                float sq  = y0 * y0 + y1 * y1;                                 \
                _Pragma("unroll")                                              \
                for (int o = 32; o >= 1; o >>= 1) {                            \
                    sum += __shfl_xor(sum, o);                                 \
                    sq  += __shfl_xor(sq, o);                                  \
                }                                                              \
                float mu  = sum * (1.0f / 128.0f);                             \
                float var = sq * (1.0f / 128.0f) - mu * mu;                    \
                float rs  = rsqrtf(var + 1e-5f) * scale;                       \
                ushort2 ov;                                                    \
                ov.x = f2bf((y0 - mu) * rs * wv.x);                            \
                ov.y = f2bf((y1 - mu) * rs * wv.y);                            \
                *(ushort2*)&C[(size_t)(bm + (RL)) * DMODEL + (h0 + (HL)) * HEADD + lane * 2] = ov; \
            }
            RLN_BODY(xv0, cs0, rl0, hl0)
            RLN_BODY(xv1, cs1, rl1, hl1)
            RLN_BODY(xv2, cs2, rl2, hl2)
            RLN_BODY(xv3, cs3, rl3, hl3)
#undef RLN_BODY
        }
    } else {
        int orow0 = bm + wm + lg * 4;
#pragma unroll
        for (int i = 0; i < 8; ++i) {
            int row = orow0 + i * 16;
            int bb = row >> 11, ss = row & (SEQ - 1);
#pragma unroll
            for (int j = 0; j < 4; ++j) {
                int col = nloc + wn + j * 16 + lr;
                int hh = col >> 7, dd = col & (HEADD - 1);
                ushort4 o4;
                o4.x = f2bf(acc[i][j][0]);
                o4.y = f2bf(acc[i][j][1]);
                o4.z = f2bf(acc[i][j][2]);
                o4.w = f2bf(acc[i][j][3]);
                *(ushort4*)(VT + ((size_t)((bb * NHEADS + hh) * HEADD + dd)) * SEQ + ss) = o4;
            }
        }
    }
}

// ---------- plain GEMM (fp32 out): C[M][N] = A[M][K] * Bw[N][K]^T ----------
__global__ __launch_bounds__(256) void gemm_bt(const unsigned short* __restrict__ A,
                                               const unsigned short* __restrict__ Bw,
                                               float* __restrict__ C,
                                               int M, int N, int K) {
    __shared__ __align__(16) unsigned short As[128 * 64];
    __shared__ __align__(16) unsigned short Bs[128 * 64];
    int tid  = threadIdx.x;
    int bm   = blockIdx.y * 128, bn = blockIdx.x * 128;
    int wave = tid >> 6, lane = tid & 63;
    int wm   = (wave >> 1) * 64, wn = (wave & 1) * 64;
    int lr   = lane & 15, lg = lane >> 4;

    f32x4 acc[4][4];
    f32x4 z = {0.f, 0.f, 0.f, 0.f};
#pragma unroll
    for (int i = 0; i < 4; ++i)
#pragma unroll
        for (int j = 0; j < 4; ++j) acc[i][j] = z;

    const unsigned short* Ab = A  + (size_t)bm * K;
    const unsigned short* Bb = Bw + (size_t)bn * K;

    for (int k0 = 0; k0 < K; k0 += GBK) {
        __syncthreads();
        stage_n<3, 4>(Ab + k0, As, K, wave, lane);
        stage_n<3, 4>(Bb + k0, Bs, K, wave, lane);
        __syncthreads();
#pragma unroll
        for (int kk = 0; kk < GBK; kk += 32) {
            int ck = (kk >> 3) + lg;
            bfv8 af[4], bf[4];
#pragma unroll
            for (int i = 0; i < 4; ++i)
                af[i] = *(const bfv8*)&As[(wm + i * 16 + lr) * 64 + (ck ^ (lr & 7)) * 8];
#pragma unroll
            for (int j = 0; j < 4; ++j)
                bf[j] = *(const bfv8*)&Bs[(wn + j * 16 + lr) * 64 + (ck ^ (lr & 7)) * 8];
#pragma unroll
            for (int i = 0; i < 4; ++i)
#pragma unroll
                for (int j = 0; j < 4; ++j)
                    acc[i][j] = __builtin_amdgcn_mfma_f32_16x16x32_bf16(af[i], bf[j], acc[i][j], 0, 0, 0);
        }
    }
    int orow0 = bm + wm + lg * 4;
    int ocol0 = bn + wn + lr;
#pragma unroll
    for (int i = 0; i < 4; ++i)
#pragma unroll
        for (int j = 0; j < 4; ++j)
#pragma unroll
            for (int r = 0; r < 4; ++r)
                C[(size_t)(orow0 + i * 16 + r) * N + ocol0 + j * 16] = acc[i][j][r];
}

// ---------- bf16 MFMA flash attention (sliding window), S^T compute ----------
#define AQT 64
#define AKT 64

__global__ __launch_bounds__(256) void attn_mfma(const unsigned short* __restrict__ qb,
                                                 const unsigned short* __restrict__ kb,
                                                 const unsigned short* __restrict__ vt,
                                                 unsigned short* __restrict__ ob,
                                                 const int* __restrict__ wptr) {
    __shared__ __align__(16) unsigned short Ks[64 * 128];    // K tile, swizzled, 16 KB
    __shared__ __align__(16) unsigned short Vs[128 * 64];    // V^T tile, swizzled, 16 KB
    __shared__ __align__(16) unsigned short Ps[4 * 16 * 64]; // per-wave P, swizzled, 8 KB
    int tid  = threadIdx.x;
    int wq   = tid >> 6, lane = tid & 63;
    int lm   = lane & 15, lg = lane >> 4;
    int lm7  = lm & 7;
    // XCD-grouped, heavy-first scheduling
    int gid  = blockIdx.x;
    int xcd  = gid & 7, slot = gid >> 3;
    int bh   = xcd * 4 + (slot >> 5);
    int b    = bh >> 4, h = bh & 15;
    int q0   = (31 - (slot & 31)) * AQT;
    int W    = *wptr;
    unsigned short* PsW = &Ps[wq * 1024];

    // Q B-fragments (16 queries/wave); 1/sqrt(d) pre-folded into Q
    bfv8 qa[4];
    {
        const unsigned short* qp = qb + (size_t)(b * SEQ + q0 + wq * 16 + lm) * DMODEL + h * HEADD + lg * 8;
#pragma unroll
        for (int kk = 0; kk < 4; ++kk) qa[kk] = *(const bfv8*)(qp + kk * 32);
    }

    f32x4 o[8];
    f32x4 z = {0.f, 0.f, 0.f, 0.f};
#pragma unroll
    for (int n = 0; n < 8; ++n) o[n] = z;
    float mrow = -1e30f, lrow = 0.f;   // per-lane state for query lm (replicated over lg)

    const unsigned short* kbase = kb + (size_t)(b * SEQ) * DMODEL + h * HEADD;
    const unsigned short* vbase = vt + (size_t)((b * NHEADS + h) * HEADD) * SEQ;

    int kt_lo = max(0, q0 - W) & ~(AKT - 1);
    int qi = q0 + wq * 16 + lm;

    for (int kt = kt_lo; kt < q0 + AQT; kt += AKT) {
        __syncthreads();
        stage_n<4, 4>(kbase + (size_t)kt * DMODEL, Ks, DMODEL, wq, lane);  // 64 x 128
        stage_n<3, 4>(vbase + kt, Vs, SEQ, wq, lane);                      // 128 x 64
        __syncthreads();

        // S^T = K Q^T : D[m=key][n=query], 64x16 per wave
        f32x4 s[4];
#pragma unroll
        for (int j = 0; j < 4; ++j) s[j] = z;
#pragma unroll
        for (int kk = 0; kk < 4; ++kk) {
#pragma unroll
            for (int j = 0; j < 4; ++j) {
                int ck = (kk * 4 + lg) ^ lm7;
                bfv8 af = *(const bfv8*)&Ks[(j * 16 + lm) * 128 + ck * 8];
                s[j] = __builtin_amdgcn_mfma_f32_16x16x32_bf16(af, qa[kk], s[j], 0, 0, 0);
            }
        }
        // mask only edge tiles (wave-uniform branch)
        if ((kt + 63 >= q0) || (kt < q0 + 63 - W)) {
#pragma unroll
            for (int j = 0; j < 4; ++j) {
                int kj0 = kt + j * 16 + lg * 4;
#pragma unroll
                for (int r = 0; r < 4; ++r) {
                    bool ok = (kj0 + r <= qi) && (kj0 + r >= qi - W);
                    s[j][r] = ok ? s[j][r] : -1e30f;
                }
            }
        }
        // online softmax: one query per lane, reduce across lg (masks 16, 32)
        float mx = -1e30f;
#pragma unroll
        for (int j = 0; j < 4; ++j)
#pragma unroll
            for (int r = 0; r < 4; ++r) mx = fmaxf(mx, s[j][r]);
        mx = fmaxf(mx, __shfl_xor(mx, 16));
        mx = fmaxf(mx, __shfl_xor(mx, 32));
        float mnew  = fmaxf(mrow, mx);
        float alpha = __expf(mrow - mnew);
        mrow = mnew;
        float ls = 0.f;
#pragma unroll
        for (int j = 0; j < 4; ++j) {
            float p0 = __expf(s[j][0] - mnew);
            float p1 = __expf(s[j][1] - mnew);
            float p2 = __expf(s[j][2] - mnew);
            float p3 = __expf(s[j][3] - mnew);
            ls += (p0 + p1) + (p2 + p3);
            // P^T C-layout rows = 4 consecutive keys -> one packed b64 store
            int c0 = (j * 2 + (lg >> 1)) ^ lm7;
            uint2 wv;
            wv.x = pk2(p0, p1);
            wv.y = pk2(p2, p3);
            *(uint2*)&PsW[lm * 64 + c0 * 8 + (lg & 1) * 4] = wv;
        }
        ls += __shfl_xor(ls, 16);
        ls += __shfl_xor(ls, 32);
        lrow = lrow * alpha + ls;
        // broadcast alpha from softmax layout (query=lm) to O layout (query=lg*4+r)
        float al[4];
#pragma unroll
        for (int r = 0; r < 4; ++r) al[r] = __shfl(alpha, lg * 4 + r);
#pragma unroll
        for (int n = 0; n < 8; ++n)
#pragma unroll
            for (int r = 0; r < 4; ++r) o[n][r] *= al[r];
        // O += P V : A = P (wave-private LDS, same-wave ordering), B = V^T
#pragma unroll
        for (int k2 = 0; k2 < 2; ++k2) {
            int cc = (k2 * 4 + lg) ^ lm7;
            bfv8 pa = *(const bfv8*)&PsW[lm * 64 + cc * 8];
#pragma unroll
            for (int n = 0; n < 8; ++n) {
                bfv8 vf = *(const bfv8*)&Vs[(n * 16 + lm) * 64 + cc * 8];
                o[n] = __builtin_amdgcn_mfma_f32_16x16x32_bf16(pa, vf, o[n], 0, 0, 0);
            }
        }
    }
    // epilogue
    float linv[4];
#pragma unroll
    for (int r = 0; r < 4; ++r) linv[r] = 1.0f / __shfl(lrow, lg * 4 + r);
    int qrow = q0 + wq * 16 + lg * 4;
    unsigned short* op = ob + (size_t)(b * SEQ + qrow) * DMODEL + h * HEADD + lm;
#pragma unroll
    for (int n = 0; n < 8; ++n)
#pragma unroll
        for (int r = 0; r < 4; ++r)
            op[(size_t)r * DMODEL + n * 16] = f2bf(o[n][r] * linv[r]);
}

// ---------- launch ----------
extern "C" void kernel_launch(void* const* d_in, const int* in_sizes, int n_in,
                              void* d_out, int out_size, void* d_ws, size_t ws_size,
                              hipStream_t stream) {
    const float* x   = (const float*)d_in[0];
    const float* wq  = (const float*)d_in[1];
    const float* wk  = (const float*)d_in[2];
    const float* wv  = (const float*)d_in[3];
    const float* wo  = (const float*)d_in[4];
    const float* qnw = (const float*)d_in[5];
    const float* knw = (const float*)d_in[6];
    const int*   wsz = (const int*)d_in[7];
    float* out = (float*)d_out;

    // workspace layout (~101 MB); cvt_all dst = [xb | w1 | w2 | w3 | w4] contiguous
    char* ws = (char*)d_ws;
    unsigned short* xb  = (unsigned short*)(ws);                 // 16.78 MB (x bf16; reused for attn out)
    unsigned short* w1  = (unsigned short*)(ws + 16777216);      // wq \  contiguous ->
    unsigned short* w4  = (unsigned short*)(ws + 41943040);      // wo
    unsigned short* qbf = (unsigned short*)(ws + 50331648);      // 16.78 MB bf16 Q
    unsigned short* kbf = (unsigned short*)(ws + 67108864);      // 16.78 MB bf16 K
    unsigned short* vtb = (unsigned short*)(ws + 83886080);      // 16.78 MB bf16 V^T
    float2* rtab = (float2*)d_out;   // RoPE table (1 MB) in d_out - dead until gemm_bt writes it

    cvt_all<<<24704, 256, 0, stream>>>(x, wq, wk, wv, wo, xb, rtab);

    gemm_qkv<<<dim3(3 * DMODEL / 256, MROWS / 256), 512, 0, stream>>>(xb, w1, qbf, kbf, vtb, qnw, knw,
                                                                      (const float2*)rtab);

    attn_mfma<<<(SEQ / AQT) * NHEADS * BATCH, 256, 0, stream>>>(qbf, kbf, vtb, xb, wsz);

    gemm_bt<<<dim3(DMODEL / 128, MROWS / 128), 256, 0, stream>>>(xb, w4, out, MROWS, DMODEL, DMODEL);
}

// Round 11
// 379.216 us; speedup vs baseline: 1.1125x; 1.0465x over previous
//
#include <hip/hip_runtime.h>

// ---------- common ----------
typedef __bf16 bfv8 __attribute__((ext_vector_type(8)));
typedef float f32x4 __attribute__((ext_vector_type(4)));

#define DMODEL 2048
#define NHEADS 16
#define HEADD 128
#define SEQ 2048
#define BATCH 2
#define MROWS (BATCH * SEQ)   // 4096

__device__ __forceinline__ unsigned short f2bf(float f) {
    unsigned int x = __float_as_uint(f);
    x += 0x7fffu + ((x >> 16) & 1u);   // round-to-nearest-even
    return (unsigned short)(x >> 16);
}
__device__ __forceinline__ float bf2f(unsigned short u) {
    return __uint_as_float((unsigned int)u << 16);
}
__device__ __forceinline__ unsigned int pk2(float a, float b) {
    return (unsigned int)f2bf(a) | ((unsigned int)f2bf(b) << 16);
}

// ---------- fused fp32 -> bf16 convert for x + 4 weights, + RoPE cos/sin table ----------
// Table blocks (bid >= 24576): 131072 (s,pair) entries as float2(cos,sin) into rtab
// (= d_out, dead until gemm_bt).
__global__ __launch_bounds__(256) void cvt_all(const float* __restrict__ x,
                                               const float* __restrict__ wq,
                                               const float* __restrict__ wk,
                                               const float* __restrict__ wv,
                                               const float* __restrict__ wo,
                                               unsigned short* __restrict__ dst,
                                               float2* __restrict__ rtab) {
    int bid = blockIdx.x;
    if (bid >= 24576) {   // RoPE table: 128 blocks x 256 thr x 4 entries
        int idx0 = (bid - 24576) * 1024 + threadIdx.x * 4;
#pragma unroll
        for (int k = 0; k < 4; ++k) {
            int idx = idx0 + k;
            int s = idx >> 6, ln = idx & 63;
            float inv = powf(10000.0f, -(float)ln * (1.0f / 64.0f));
            float ang = (float)s * inv;
            float sn, c;
            sincosf(ang, &sn, &c);
            rtab[idx] = make_float2(c, sn);
        }
        return;
    }
    const float* s;
    int off;
    if (bid < 8192)       { s = x;  off = bid; }
    else if (bid < 12288) { s = wq; off = bid - 8192; }
    else if (bid < 16384) { s = wk; off = bid - 12288; }
    else if (bid < 20480) { s = wv; off = bid - 16384; }
    else                  { s = wo; off = bid - 20480; }
    int i = off * 1024 + threadIdx.x * 4;
    float4 v = *(const float4*)(s + i);
    ushort4 o;
    o.x = f2bf(v.x); o.y = f2bf(v.y); o.z = f2bf(v.z); o.w = f2bf(v.w);
    *(ushort4*)(dst + (size_t)bid * 1024 + threadIdx.x * 4) = o;
}

// ============================================================
// global_load_lds staging into XOR-swizzled unpadded LDS.
// CPRL = log2(16B-chunks per row). Stored chunk c holds global
// chunk g = c ^ (row & 7).  128B rows -> proven 0 bank conflicts.
// ============================================================
template <int CPRL, int ITERS>
__device__ __forceinline__ void stage_n(const unsigned short* __restrict__ gbase,
                                        unsigned short* lds, size_t strideShorts,
                                        int wave, int lane) {
#pragma unroll
    for (int i = 0; i < ITERS; ++i) {
        int L = wave * (64 * ITERS) + i * 64 + lane;
        int m = L >> CPRL, c = L & ((1 << CPRL) - 1);
        int g = c ^ (m & 7);
        const unsigned short* gp = gbase + (size_t)m * strideShorts + g * 8;
        __builtin_amdgcn_global_load_lds(
            (const __attribute__((address_space(1))) unsigned int*)gp,
            (__attribute__((address_space(3))) unsigned int*)(lds + (size_t)(wave * (64 * ITERS) + i * 64) * 8),
            16, 0, 0);
    }
}

#define GBK 64
#define QNT (DMODEL / 64)   // 32 K-tiles

// ============================================================
// fused QKV GEMM + RoPE + per-head LayerNorm epilogue.
// 256x256 tile / 8-wave / round-2 K-loop (best measured: 125.7 us).
// Epilogue history: r8 serial chain = +49us; r9 rtab (sincosf gone) =
// +45us -> latency-chain bound, not VALU; r10 4-wide ILP = +24us.
// r11: 32-lanes-per-head. Each lane holds ushort4 (4 head elements,
// 2 RoPE pairs) -> half-wave covers a head; one wave instruction
// processes TWO (row,head) units (half 0 = head h0, half 1 = h0+1,
// same row). 32 body-calls/wave (was 64), 5-level shfl (was 6),
// float4 rtab/weight loads, ushort4 stores. + retained 4-wide ILP.
//
// K-loop schedule per tile t (slot s=t&1), race-free, r2-proven:
//   PhA: stage hB0(t+1)->s^1; reads a03/b01; 16 MFMA (prio 1)
//   PhB: stage hB1(t+1)->s^1; reads a47/b23; 16 MFMA
//   lgkm(0); barrier   <- all waves done reading slot s
//   PhC: stage hA0(t+2)->s; 16 MFMA    PhD: stage hA1(t+2)->s; 16 MFMA
//   vmcnt(4); barrier  <- tile t+1 landed; hA(t+2) in flight
// LDS union: K-loop LA|LB = 128 KB; epilogue LC = 256x264x2 = 132 KB.
// ============================================================
__global__ __launch_bounds__(512, 2) void gemm_qkv(const unsigned short* __restrict__ A,
                                                   const unsigned short* __restrict__ Bw,
                                                   unsigned short* __restrict__ Qb,
                                                   unsigned short* __restrict__ Kb,
                                                   unsigned short* __restrict__ VT,
                                                   const float* __restrict__ qnw,
                                                   const float* __restrict__ knw,
                                                   const float2* __restrict__ rtab) {
    __shared__ __align__(16) unsigned char LDSraw[135168];
    unsigned short (*LA)[256 * 64] = (unsigned short (*)[256 * 64])(LDSraw);           // [2][16384]
    unsigned short (*LB)[256 * 64] = (unsigned short (*)[256 * 64])(LDSraw + 65536);   // [2][16384]
    unsigned short* LC = (unsigned short*)LDSraw;                                      // [256][264]
    const int K = DMODEL;
    int tid  = threadIdx.x;
    int wave = tid >> 6, lane = tid & 63;
    int wr = wave >> 2, wc = wave & 3;        // 2 x 4 wave grid
    int wm = wr * 128, wn = wc * 64;          // per-wave C = 128 x 64
    int lr = lane & 15, lg = lane >> 4, lsw = lr & 7;
    int bm = blockIdx.y * 256, bn = blockIdx.x * 256;

    const unsigned short* Ab = A  + (size_t)bm * K;
    const unsigned short* Bb = Bw + (size_t)bn * K;

    f32x4 acc[8][4];
    f32x4 z = {0.f, 0.f, 0.f, 0.f};
#pragma unroll
    for (int i = 0; i < 8; ++i)
#pragma unroll
        for (int j = 0; j < 4; ++j) acc[i][j] = z;

    // ---- prologue: A(0) both halves, B(0) both halves, A(1) both halves (12 loads/thread)
    stage_n<3, 2>(Ab,                        LA[0],            K, wave, lane);
    stage_n<3, 2>(Ab + (size_t)128 * K,      LA[0] + 128 * 64, K, wave, lane);
    stage_n<3, 2>(Bb,                        LB[0],            K, wave, lane);
    stage_n<3, 2>(Bb + (size_t)128 * K,      LB[0] + 128 * 64, K, wave, lane);
    stage_n<3, 2>(Ab + 64,                   LA[1],            K, wave, lane);
    stage_n<3, 2>(Ab + (size_t)128 * K + 64, LA[1] + 128 * 64, K, wave, lane);
    asm volatile("s_waitcnt vmcnt(4)" ::: "memory");   // tile 0 landed; hA(1) in flight
    __builtin_amdgcn_s_barrier();
    __builtin_amdgcn_sched_barrier(0);

#pragma unroll 2
    for (int t = 0; t < QNT; ++t) {
        const unsigned short* As = LA[t & 1];
        const unsigned short* Bs = LB[t & 1];
        unsigned short* AsN = LA[t & 1];           // A(t+2) -> same slot
        unsigned short* BsN = LB[(t & 1) ^ 1];     // B(t+1) -> other slot
        int tA = t + 2; if (tA >= QNT) tA = t;     // tail dummies keep vmcnt uniform
        int tB = t + 1; if (tB >= QNT) tB = t - 1; // (same parity -> same slot, no reader)

        bfv8 a03[4][2], a47[4][2], b01[2][2], b23[2][2];

        // ---- phase A: stage hB0(t+1); read a[0..3], b[0..1]; MFMA (i0-3 x j0-1)
        stage_n<3, 2>(Bb + (size_t)tB * 64, BsN, K, wave, lane);
#pragma unroll
        for (int i = 0; i < 4; ++i)
#pragma unroll
            for (int ks = 0; ks < 2; ++ks)
                a03[i][ks] = *(const bfv8*)&As[(wm + i * 16 + lr) * 64 + ((ks * 4 + lg) ^ lsw) * 8];
#pragma unroll
        for (int j = 0; j < 2; ++j)
#pragma unroll
            for (int ks = 0; ks < 2; ++ks)
                b01[j][ks] = *(const bfv8*)&Bs[(wn + j * 16 + lr) * 64 + ((ks * 4 + lg) ^ lsw) * 8];
        __builtin_amdgcn_sched_barrier(0);
        __builtin_amdgcn_s_setprio(1);
#pragma unroll
        for (int i = 0; i < 4; ++i)
#pragma unroll
            for (int j = 0; j < 2; ++j)
#pragma unroll
                for (int ks = 0; ks < 2; ++ks)
                    acc[i][j] = __builtin_amdgcn_mfma_f32_16x16x32_bf16(a03[i][ks], b01[j][ks], acc[i][j], 0, 0, 0);
        __builtin_amdgcn_s_setprio(0);
        __builtin_amdgcn_sched_barrier(0);

        // ---- phase B: stage hB1(t+1); read a[4..7], b[2..3]; MFMA (i0-3 x j2-3)
        stage_n<3, 2>(Bb + (size_t)128 * K + tB * 64, BsN + 128 * 64, K, wave, lane);
#pragma unroll
        for (int i = 0; i < 4; ++i)
#pragma unroll
            for (int ks = 0; ks < 2; ++ks)
                a47[i][ks] = *(const bfv8*)&As[(wm + 64 + i * 16 + lr) * 64 + ((ks * 4 + lg) ^ lsw) * 8];
#pragma unroll
        for (int j = 0; j < 2; ++j)
#pragma unroll
            for (int ks = 0; ks < 2; ++ks)
                b23[j][ks] = *(const bfv8*)&Bs[(wn + 32 + j * 16 + lr) * 64 + ((ks * 4 + lg) ^ lsw) * 8];
        __builtin_amdgcn_sched_barrier(0);
        __builtin_amdgcn_s_setprio(1);
#pragma unroll
        for (int i = 0; i < 4; ++i)
#pragma unroll
            for (int j = 0; j < 2; ++j)
#pragma unroll
                for (int ks = 0; ks < 2; ++ks)
                    acc[i][2 + j] = __builtin_amdgcn_mfma_f32_16x16x32_bf16(a03[i][ks], b23[j][ks], acc[i][2 + j], 0, 0, 0);
        __builtin_amdgcn_s_setprio(0);
        __builtin_amdgcn_sched_barrier(0);

        asm volatile("s_waitcnt lgkmcnt(0)" ::: "memory");  // my reads of slot s drained
        __builtin_amdgcn_s_barrier();                        // ... all waves' reads drained
        __builtin_amdgcn_sched_barrier(0);

        // ---- phase C: stage hA0(t+2) into freed slot; MFMA (i4-7 x j0-1)
        stage_n<3, 2>(Ab + (size_t)tA * 64, AsN, K, wave, lane);
        __builtin_amdgcn_sched_barrier(0);
        __builtin_amdgcn_s_setprio(1);
#pragma unroll
        for (int i = 0; i < 4; ++i)
#pragma unroll
            for (int j = 0; j < 2; ++j)
#pragma unroll
                for (int ks = 0; ks < 2; ++ks)
                    acc[4 + i][j] = __builtin_amdgcn_mfma_f32_16x16x32_bf16(a47[i][ks], b01[j][ks], acc[4 + i][j], 0, 0, 0);
        __builtin_amdgcn_s_setprio(0);
        __builtin_amdgcn_sched_barrier(0);

        // ---- phase D: stage hA1(t+2); MFMA (i4-7 x j2-3)
        stage_n<3, 2>(Ab + (size_t)128 * K + tA * 64, AsN + 128 * 64, K, wave, lane);
        __builtin_amdgcn_sched_barrier(0);
        __builtin_amdgcn_s_setprio(1);
#pragma unroll
        for (int i = 0; i < 4; ++i)
#pragma unroll
            for (int j = 0; j < 2; ++j)
#pragma unroll
                for (int ks = 0; ks < 2; ++ks)
                    acc[4 + i][2 + j] = __builtin_amdgcn_mfma_f32_16x16x32_bf16(a47[i][ks], b23[j][ks], acc[4 + i][2 + j], 0, 0, 0);
        __builtin_amdgcn_s_setprio(0);
        __builtin_amdgcn_sched_barrier(0);

        asm volatile("s_waitcnt vmcnt(4)" ::: "memory");   // tile t+1 landed; hA(t+2) in flight
        __builtin_amdgcn_s_barrier();
        __builtin_amdgcn_sched_barrier(0);
    }
    asm volatile("s_waitcnt vmcnt(0)" ::: "memory");  // drain tail dummies before LDS reuse

    // ---- epilogue
    int region = bn >> 11;          // block-uniform: 0=Q 1=K 2=V (2048 % 256 == 0)
    int nloc   = bn & 2047;
    if (region < 2) {
        // stage fragments to padded LDS for cross-wave RoPE+LayerNorm
        __syncthreads();   // all waves past K-loop before LC overwrites LA/LB
#pragma unroll
        for (int i = 0; i < 8; ++i)
#pragma unroll
            for (int j = 0; j < 4; ++j)
#pragma unroll
                for (int r = 0; r < 4; ++r)
                    LC[(wm + lg * 4 + i * 16 + r) * 264 + wn + j * 16 + lr] = f2bf(acc[i][j][r]);
        __syncthreads();
        unsigned short* C = region ? Kb : Qb;
        const float* w = region ? knw : qnw;
        float scale = region ? 1.0f : 0.08838834764831845f;   // fold 1/sqrt(128) into Q
        // 32-lanes-per-head: lane ln = lane&31 owns head elements 4ln..4ln+3
        // (RoPE pairs 2ln, 2ln+1); half = lane>>5 selects which of the block's
        // 2 heads. One wave instruction covers 2 (row,head) units.
        int half = lane >> 5, ln = lane & 31;
        int h0 = nloc >> 7;   // first of the 2 heads this block owns
        float4 wvv = *(const float4*)(w + ln * 4);   // LN weights, 16B aligned
        int hoff = half * 128;                        // LC col offset of this half's head
        size_t gcol = (size_t)(h0 + half) * HEADD + ln * 4;
        int rbase = wave * 32;                        // 32 rows per wave
#define RLN4(XV, CS, RL)                                                      \
        {                                                                     \
            float x0 = bf2f((XV).x), x1 = bf2f((XV).y);                       \
            float x2 = bf2f((XV).z), x3 = bf2f((XV).w);                       \
            float y0 = x0 * (CS).x - x1 * (CS).y;                             \
            float y1 = x0 * (CS).y + x1 * (CS).x;                             \
            float y2 = x2 * (CS).z - x3 * (CS).w;                             \
            float y3 = x2 * (CS).w + x3 * (CS).z;                             \
            float sum = (y0 + y1) + (y2 + y3);                                \
            float sq  = (y0 * y0 + y1 * y1) + (y2 * y2 + y3 * y3);            \
            _Pragma("unroll")                                                 \
            for (int o = 16; o >= 1; o >>= 1) {                               \
                sum += __shfl_xor(sum, o);                                    \
                sq  += __shfl_xor(sq, o);                                     \
            }                                                                 \
            float mu  = sum * (1.0f / 128.0f);                                \
            float var = sq * (1.0f / 128.0f) - mu * mu;                       \
            float rs  = rsqrtf(var + 1e-5f) * scale;                          \
            ushort4 ov;                                                       \
            ov.x = f2bf((y0 - mu) * rs * wvv.x);                              \
            ov.y = f2bf((y1 - mu) * rs * wvv.y);                              \
            ov.z = f2bf((y2 - mu) * rs * wvv.z);                              \
            ov.w = f2bf((y3 - mu) * rs * wvv.w);                              \
            *(ushort4*)&C[(size_t)(bm + (RL)) * DMODEL + gcol] = ov;          \
        }
#pragma unroll 1
        for (int g = 0; g < 8; ++g) {
            int r0 = rbase + g * 4;   // 4-wide ILP over consecutive rows
            ushort4 xa = *(const ushort4*)&LC[(r0 + 0) * 264 + hoff + ln * 4];
            ushort4 xb = *(const ushort4*)&LC[(r0 + 1) * 264 + hoff + ln * 4];
            ushort4 xc = *(const ushort4*)&LC[(r0 + 2) * 264 + hoff + ln * 4];
            ushort4 xd = *(const ushort4*)&LC[(r0 + 3) * 264 + hoff + ln * 4];
            // rtab row = global row (bm+r) & (SEQ-1); float4 = pairs 2ln,2ln+1 (16B aligned)
            float4 ca = *(const float4*)&rtab[(size_t)((bm + r0 + 0) & (SEQ - 1)) * 64 + ln * 2];
            float4 cb = *(const float4*)&rtab[(size_t)((bm + r0 + 1) & (SEQ - 1)) * 64 + ln * 2];
            float4 cc = *(const float4*)&rtab[(size_t)((bm + r0 + 2) & (SEQ - 1)) * 64 + ln * 2];
            float4 cd = *(const float4*)&rtab[(size_t)((bm + r0 + 3) & (SEQ - 1)) * 64 + ln * 2];
            RLN4(xa, ca, r0 + 0)
            RLN4(xb, cb, r0 + 1)
            RLN4(xc, cc, r0 + 2)
            RLN4(xd, cd, r0 + 3)
        }
#undef RLN4
    } else {
        int orow0 = bm + wm + lg * 4;
#pragma unroll
        for (int i = 0; i < 8; ++i) {
            int row = orow0 + i * 16;
            int bb = row >> 11, ss = row & (SEQ - 1);
#pragma unroll
            for (int j = 0; j < 4; ++j) {
                int col = nloc + wn + j * 16 + lr;
                int hh = col >> 7, dd = col & (HEADD - 1);
                ushort4 o4;
                o4.x = f2bf(acc[i][j][0]);
                o4.y = f2bf(acc[i][j][1]);
                o4.z = f2bf(acc[i][j][2]);
                o4.w = f2bf(acc[i][j][3]);
                *(ushort4*)(VT + ((size_t)((bb * NHEADS + hh) * HEADD + dd)) * SEQ + ss) = o4;
            }
        }
    }
}

// ---------- plain GEMM (fp32 out): C[M][N] = A[M][K] * Bw[N][K]^T ----------
__global__ __launch_bounds__(256) void gemm_bt(const unsigned short* __restrict__ A,
                                               const unsigned short* __restrict__ Bw,
                                               float* __restrict__ C,
                                               int M, int N, int K) {
    __shared__ __align__(16) unsigned short As[128 * 64];
    __shared__ __align__(16) unsigned short Bs[128 * 64];
    int tid  = threadIdx.x;
    int bm   = blockIdx.y * 128, bn = blockIdx.x * 128;
    int wave = tid >> 6, lane = tid & 63;
    int wm   = (wave >> 1) * 64, wn = (wave & 1) * 64;
    int lr   = lane & 15, lg = lane >> 4;

    f32x4 acc[4][4];
    f32x4 z = {0.f, 0.f, 0.f, 0.f};
#pragma unroll
    for (int i = 0; i < 4; ++i)
#pragma unroll
        for (int j = 0; j < 4; ++j) acc[i][j] = z;

    const unsigned short* Ab = A  + (size_t)bm * K;
    const unsigned short* Bb = Bw + (size_t)bn * K;

    for (int k0 = 0; k0 < K; k0 += GBK) {
        __syncthreads();
        stage_n<3, 4>(Ab + k0, As, K, wave, lane);
        stage_n<3, 4>(Bb + k0, Bs, K, wave, lane);
        __syncthreads();
#pragma unroll
        for (int kk = 0; kk < GBK; kk += 32) {
            int ck = (kk >> 3) + lg;
            bfv8 af[4], bf[4];
#pragma unroll
            for (int i = 0; i < 4; ++i)
                af[i] = *(const bfv8*)&As[(wm + i * 16 + lr) * 64 + (ck ^ (lr & 7)) * 8];
#pragma unroll
            for (int j = 0; j < 4; ++j)
                bf[j] = *(const bfv8*)&Bs[(wn + j * 16 + lr) * 64 + (ck ^ (lr & 7)) * 8];
#pragma unroll
            for (int i = 0; i < 4; ++i)
#pragma unroll
                for (int j = 0; j < 4; ++j)
                    acc[i][j] = __builtin_amdgcn_mfma_f32_16x16x32_bf16(af[i], bf[j], acc[i][j], 0, 0, 0);
        }
    }
    int orow0 = bm + wm + lg * 4;
    int ocol0 = bn + wn + lr;
#pragma unroll
    for (int i = 0; i < 4; ++i)
#pragma unroll
        for (int j = 0; j < 4; ++j)
#pragma unroll
            for (int r = 0; r < 4; ++r)
                C[(size_t)(orow0 + i * 16 + r) * N + ocol0 + j * 16] = acc[i][j][r];
}

// ---------- bf16 MFMA flash attention (sliding window), S^T compute ----------
#define AQT 64
#define AKT 64

__global__ __launch_bounds__(256) void attn_mfma(const unsigned short* __restrict__ qb,
                                                 const unsigned short* __restrict__ kb,
                                                 const unsigned short* __restrict__ vt,
                                                 unsigned short* __restrict__ ob,
                                                 const int* __restrict__ wptr) {
    __shared__ __align__(16) unsigned short Ks[64 * 128];    // K tile, swizzled, 16 KB
    __shared__ __align__(16) unsigned short Vs[128 * 64];    // V^T tile, swizzled, 16 KB
    __shared__ __align__(16) unsigned short Ps[4 * 16 * 64]; // per-wave P, swizzled, 8 KB
    int tid  = threadIdx.x;
    int wq   = tid >> 6, lane = tid & 63;
    int lm   = lane & 15, lg = lane >> 4;
    int lm7  = lm & 7;
    // XCD-grouped, heavy-first scheduling
    int gid  = blockIdx.x;
    int xcd  = gid & 7, slot = gid >> 3;
    int bh   = xcd * 4 + (slot >> 5);
    int b    = bh >> 4, h = bh & 15;
    int q0   = (31 - (slot & 31)) * AQT;
    int W    = *wptr;
    unsigned short* PsW = &Ps[wq * 1024];

    // Q B-fragments (16 queries/wave); 1/sqrt(d) pre-folded into Q
    bfv8 qa[4];
    {
        const unsigned short* qp = qb + (size_t)(b * SEQ + q0 + wq * 16 + lm) * DMODEL + h * HEADD + lg * 8;
#pragma unroll
        for (int kk = 0; kk < 4; ++kk) qa[kk] = *(const bfv8*)(qp + kk * 32);
    }

    f32x4 o[8];
    f32x4 z = {0.f, 0.f, 0.f, 0.f};
#pragma unroll
    for (int n = 0; n < 8; ++n) o[n] = z;
    float mrow = -1e30f, lrow = 0.f;   // per-lane state for query lm (replicated over lg)

    const unsigned short* kbase = kb + (size_t)(b * SEQ) * DMODEL + h * HEADD;
    const unsigned short* vbase = vt + (size_t)((b * NHEADS + h) * HEADD) * SEQ;

    int kt_lo = max(0, q0 - W) & ~(AKT - 1);
    int qi = q0 + wq * 16 + lm;

    for (int kt = kt_lo; kt < q0 + AQT; kt += AKT) {
        __syncthreads();
        stage_n<4, 4>(kbase + (size_t)kt * DMODEL, Ks, DMODEL, wq, lane);  // 64 x 128
        stage_n<3, 4>(vbase + kt, Vs, SEQ, wq, lane);                      // 128 x 64
        __syncthreads();

        // S^T = K Q^T : D[m=key][n=query], 64x16 per wave
        f32x4 s[4];
#pragma unroll
        for (int j = 0; j < 4; ++j) s[j] = z;
#pragma unroll
        for (int kk = 0; kk < 4; ++kk) {
#pragma unroll
            for (int j = 0; j < 4; ++j) {
                int ck = (kk * 4 + lg) ^ lm7;
                bfv8 af = *(const bfv8*)&Ks[(j * 16 + lm) * 128 + ck * 8];
                s[j] = __builtin_amdgcn_mfma_f32_16x16x32_bf16(af, qa[kk], s[j], 0, 0, 0);
            }
        }
        // mask only edge tiles (wave-uniform branch)
        if ((kt + 63 >= q0) || (kt < q0 + 63 - W)) {
#pragma unroll
            for (int j = 0; j < 4; ++j) {
                int kj0 = kt + j * 16 + lg * 4;
#pragma unroll
                for (int r = 0; r < 4; ++r) {
                    bool ok = (kj0 + r <= qi) && (kj0 + r >= qi - W);
                    s[j][r] = ok ? s[j][r] : -1e30f;
                }
            }
        }
        // online softmax: one query per lane, reduce across lg (masks 16, 32)
        float mx = -1e30f;
#pragma unroll
        for (int j = 0; j < 4; ++j)
#pragma unroll
            for (int r = 0; r < 4; ++r) mx = fmaxf(mx, s[j][r]);
        mx = fmaxf(mx, __shfl_xor(mx, 16));
        mx = fmaxf(mx, __shfl_xor(mx, 32));
        float mnew  = fmaxf(mrow, mx);
        float alpha = __expf(mrow - mnew);
        mrow = mnew;
        float ls = 0.f;
#pragma unroll
        for (int j = 0; j < 4; ++j) {
            float p0 = __expf(s[j][0] - mnew);
            float p1 = __expf(s[j][1] - mnew);
            float p2 = __expf(s[j][2] - mnew);
            float p3 = __expf(s[j][3] - mnew);
            ls += (p0 + p1) + (p2 + p3);
            // P^T C-layout rows = 4 consecutive keys -> one packed b64 store
            int c0 = (j * 2 + (lg >> 1)) ^ lm7;
            uint2 wv;
            wv.x = pk2(p0, p1);
            wv.y = pk2(p2, p3);
            *(uint2*)&PsW[lm * 64 + c0 * 8 + (lg & 1) * 4] = wv;
        }
        ls += __shfl_xor(ls, 16);
        ls += __shfl_xor(ls, 32);
        lrow = lrow * alpha + ls;
        // broadcast alpha from softmax layout (query=lm) to O layout (query=lg*4+r)
        float al[4];
#pragma unroll
        for (int r = 0; r < 4; ++r) al[r] = __shfl(alpha, lg * 4 + r);
#pragma unroll
        for (int n = 0; n < 8; ++n)
#pragma unroll
            for (int r = 0; r < 4; ++r) o[n][r] *= al[r];
        // O += P V : A = P (wave-private LDS, same-wave ordering), B = V^T
#pragma unroll
        for (int k2 = 0; k2 < 2; ++k2) {
            int cc = (k2 * 4 + lg) ^ lm7;
            bfv8 pa = *(const bfv8*)&PsW[lm * 64 + cc * 8];
#pragma unroll
            for (int n = 0; n < 8; ++n) {
                bfv8 vf = *(const bfv8*)&Vs[(n * 16 + lm) * 64 + cc * 8];
                o[n] = __builtin_amdgcn_mfma_f32_16x16x32_bf16(pa, vf, o[n], 0, 0, 0);
            }
        }
    }
    // epilogue
    float linv[4];
#pragma unroll
    for (int r = 0; r < 4; ++r) linv[r] = 1.0f / __shfl(lrow, lg * 4 + r);
    int qrow = q0 + wq * 16 + lg * 4;
    unsigned short* op = ob + (size_t)(b * SEQ + qrow) * DMODEL + h * HEADD + lm;
#pragma unroll
    for (int n = 0; n < 8; ++n)
#pragma unroll
        for (int r = 0; r < 4; ++r)
            op[(size_t)r * DMODEL + n * 16] = f2bf(o[n][r] * linv[r]);
}

// ---------- launch ----------
extern "C" void kernel_launch(void* const* d_in, const int* in_sizes, int n_in,
                              void* d_out, int out_size, void* d_ws, size_t ws_size,
                              hipStream_t stream) {
    const float* x   = (const float*)d_in[0];
    const float* wq  = (const float*)d_in[1];
    const float* wk  = (const float*)d_in[2];
    const float* wv  = (const float*)d_in[3];
    const float* wo  = (const float*)d_in[4];
    const float* qnw = (const float*)d_in[5];
    const float* knw = (const float*)d_in[6];
    const int*   wsz = (const int*)d_in[7];
    float* out = (float*)d_out;

    // workspace layout (~101 MB); cvt_all dst = [xb | w1 | w2 | w3 | w4] contiguous
    char* ws = (char*)d_ws;
    unsigned short* xb  = (unsigned short*)(ws);                 // 16.78 MB (x bf16; reused for attn out)
    unsigned short* w1  = (unsigned short*)(ws + 16777216);      // wq \  contiguous ->
    unsigned short* w4  = (unsigned short*)(ws + 41943040);      // wo
    unsigned short* qbf = (unsigned short*)(ws + 50331648);      // 16.78 MB bf16 Q
    unsigned short* kbf = (unsigned short*)(ws + 67108864);      // 16.78 MB bf16 K
    unsigned short* vtb = (unsigned short*)(ws + 83886080);      // 16.78 MB bf16 V^T
    float2* rtab = (float2*)d_out;   // RoPE table (1 MB) in d_out - dead until gemm_bt writes it

    cvt_all<<<24704, 256, 0, stream>>>(x, wq, wk, wv, wo, xb, rtab);

    gemm_qkv<<<dim3(3 * DMODEL / 256, MROWS / 256), 512, 0, stream>>>(xb, w1, qbf, kbf, vtb, qnw, knw,
                                                                      (const float2*)rtab);

    attn_mfma<<<(SEQ / AQT) * NHEADS * BATCH, 256, 0, stream>>>(qbf, kbf, vtb, xb, wsz);

    gemm_bt<<<dim3(DMODEL / 128, MROWS / 128), 256, 0, stream>>>(xb, w4, out, MROWS, DMODEL, DMODEL);
}